// Round 5
// baseline (530.707 us; speedup 1.0000x reference)
//
#include <hip/hip_runtime.h>
#include <hip/hip_bf16.h>

#define NL 4096   // 64*64 low-res pixels
#define HH 32
#define WH 32
#define NBLK 512

typedef __attribute__((ext_vector_type(8))) short s8v;   // 8 bf16 MFMA A/B frag
typedef __attribute__((ext_vector_type(4))) short s4v;   // 4 bf16 (8B)
typedef __attribute__((ext_vector_type(4))) float f32x4; // MFMA C/D frag

static __device__ inline unsigned short f2bf(float x) {
  __hip_bfloat16 h = __float2bfloat16(x);   // RNE
  return *reinterpret_cast<unsigned short*>(&h);
}
static __device__ inline float bfbits2f(unsigned int lo16) {
  unsigned int u = lo16 << 16;
  return *reinterpret_cast<float*>(&u);
}

struct Params {
  const float *low, *high;
  const float *W1, *b1, *W2, *b2, *Wq, *bq, *Wk, *bk, *Wv, *bv, *Woff, *boff, *Wb;
  const float *gamma, *beta, *rmean, *rvar;
  float* out;
  short *xin, *qf, *vf, *v_t, *attn_t, *wc;
  float *q_t, *k_t, *off_t;
  unsigned* bar;          // [0]=arrive count, [1]=generation (memset to 0 pre-launch)
};

union Smem {
  short prep[64 * 65];                               // 8320 B
  struct { float w[4][32][4]; int i[4][32][4]; } at; // 4096 B
};

// ---------------------------------------------------------------------------
// Software grid barrier: sense-reversing, device-scope atomics.
// All NBLK blocks guaranteed co-resident (launch_bounds(256,2) -> 2 blk/CU).
// ---------------------------------------------------------------------------
__device__ __forceinline__ void grid_barrier(unsigned* bar) {
  __syncthreads();
  if (threadIdx.x == 0) {
    __threadfence();   // release: flush this block's writes to device scope
    unsigned gen = __hip_atomic_load(&bar[1], __ATOMIC_ACQUIRE,
                                     __HIP_MEMORY_SCOPE_AGENT);
    unsigned prev = __hip_atomic_fetch_add(&bar[0], 1u, __ATOMIC_ACQ_REL,
                                           __HIP_MEMORY_SCOPE_AGENT);
    if (prev + 1u == NBLK) {
      __hip_atomic_store(&bar[0], 0u, __ATOMIC_RELAXED, __HIP_MEMORY_SCOPE_AGENT);
      __hip_atomic_store(&bar[1], gen + 1u, __ATOMIC_RELEASE,
                         __HIP_MEMORY_SCOPE_AGENT);
    } else {
      while (__hip_atomic_load(&bar[1], __ATOMIC_ACQUIRE,
                               __HIP_MEMORY_SCOPE_AGENT) == gen) {
        __builtin_amdgcn_s_sleep(1);
      }
    }
    __threadfence();   // acquire: invalidate stale cached lines
  }
  __syncthreads();
}

// ---------------------------------------------------------------------------
// MFMA GEMM core: Y[n][o] = sum_k W[o][k]*X[n][k]. Wave tile 16n x (MF*16)m.
// MODE 0: bf16 pixel-major [n][M] | 1: f32 pixel-major [n][M]
// MODE 2: f32 channel-major [b][M][4096] + BN + ReLU
// ---------------------------------------------------------------------------
template <int M, int K1, int K2, int MF, int MODE>
__device__ __forceinline__ void gemm_core(
    const short* __restrict__ W, const float* __restrict__ bias,
    const short* __restrict__ B1, int sB1,
    const short* __restrict__ B2, int sB2,
    void* __restrict__ Yv,
    const float* __restrict__ gamma, const float* __restrict__ beta,
    const float* __restrict__ rmean, const float* __restrict__ rvar,
    int bx, int by) {
  constexpr int K = K1 + K2;
  const int tid = threadIdx.x;
  const int wave = tid >> 6, lane = tid & 63;
  const int quad = lane >> 4, id = lane & 15;
  const int n = bx * 64 + wave * 16 + id;
  const int m0 = by * (MF * 16);

  f32x4 acc[MF];
#pragma unroll
  for (int mf = 0; mf < MF; mf++) acc[mf] = (f32x4){0.f, 0.f, 0.f, 0.f};

  const short* ap[MF];
#pragma unroll
  for (int mf = 0; mf < MF; mf++)
    ap[mf] = W + (size_t)(m0 + mf * 16 + id) * K + quad * 8;
  const short* bp = B1 + (size_t)n * sB1 + quad * 8;

#pragma unroll
  for (int kk = 0; kk < K1; kk += 32) {
    s8v bfr = *(const s8v*)(bp + kk);
    s8v a[MF];
#pragma unroll
    for (int mf = 0; mf < MF; mf++) a[mf] = *(const s8v*)(ap[mf] + kk);
#pragma unroll
    for (int mf = 0; mf < MF; mf++)
      acc[mf] = __builtin_amdgcn_mfma_f32_16x16x32_bf16(a[mf], bfr, acc[mf], 0, 0, 0);
  }
  if constexpr (K2 > 0) {
    const short* bp2 = B2 + (size_t)n * sB2 + quad * 8;
#pragma unroll
    for (int kk = 0; kk < K2; kk += 32) {
      s8v bfr = *(const s8v*)(bp2 + kk);
      s8v a[MF];
#pragma unroll
      for (int mf = 0; mf < MF; mf++) a[mf] = *(const s8v*)(ap[mf] + K1 + kk);
#pragma unroll
      for (int mf = 0; mf < MF; mf++)
        acc[mf] = __builtin_amdgcn_mfma_f32_16x16x32_bf16(a[mf], bfr, acc[mf], 0, 0, 0);
    }
  }

#pragma unroll
  for (int mf = 0; mf < MF; mf++) {
    int mbase = m0 + mf * 16 + quad * 4;
    f32x4 v = acc[mf];
    if (bias) {
#pragma unroll
      for (int r = 0; r < 4; r++) v[r] += bias[mbase + r];
    }
    if constexpr (MODE == 0) {
      s4v o;
#pragma unroll
      for (int r = 0; r < 4; r++) o[r] = (short)f2bf(v[r]);
      *(s4v*)((short*)Yv + (size_t)n * M + mbase) = o;
    } else if constexpr (MODE == 1) {
      *(f32x4*)((float*)Yv + (size_t)n * M + mbase) = v;
    } else {
      int b = n >> 12, nlow = n & (NL - 1);
#pragma unroll
      for (int r = 0; r < 4; r++) {
        int o = mbase + r;
        float s  = gamma[o] * rsqrtf(rvar[o] + 1e-5f);
        float sh = beta[o] - rmean[o] * s;
        ((float*)Yv)[((size_t)b * M + o) * NL + nlow] =
            fmaxf(fmaf(v[r], s, sh), 0.f);
      }
    }
  }
}

// ---------------------------------------------------------------------------
// prep unit: bilinear 2x upsample of high (c0<256) or copy of low (c0>=256),
// transposed to bf16 pixel-major xin[b][n][512].
// ---------------------------------------------------------------------------
__device__ __forceinline__ void prep_unit(const Params& p, int ux, int uy, int uz,
                                          short* lds /* [64][65] */) {
  const int b = uz;
  const int n0 = ux * 64, c0 = uy * 64;
  const int nl = threadIdx.x & 63, cl = threadIdx.x >> 6;

  if (c0 < 256) {
    int n = n0 + nl;
    int y = n >> 6, x = n & 63;
    float sx = x * 0.5f - 0.25f;
    float sy = y * 0.5f - 0.25f;
    float x0f = floorf(sx), y0f = floorf(sy);
    float wx = sx - x0f, wy = sy - y0f;
    int x0 = (int)x0f, y0 = (int)y0f;
    int x0c = min(WH - 1, max(0, x0)), x1c = min(WH - 1, max(0, x0 + 1));
    int y0c = min(HH - 1, max(0, y0)), y1c = min(HH - 1, max(0, y0 + 1));
    float w00 = (1.f - wy) * (1.f - wx), w01 = (1.f - wy) * wx;
    float w10 = wy * (1.f - wx),         w11 = wy * wx;
#pragma unroll
    for (int i = 0; i < 16; i++) {
      int c = c0 + cl + 4 * i;
      const float* f = p.high + ((size_t)b * 256 + c) * (HH * WH);
      float v = w00 * f[y0c * WH + x0c] + w01 * f[y0c * WH + x1c]
              + w10 * f[y1c * WH + x0c] + w11 * f[y1c * WH + x1c];
      lds[nl * 65 + cl + 4 * i] = (short)f2bf(v);
    }
  } else {
#pragma unroll
    for (int i = 0; i < 16; i++) {
      int c = c0 - 256 + cl + 4 * i;
      lds[nl * 65 + cl + 4 * i] =
          (short)f2bf(p.low[((size_t)b * 256 + c) * NL + n0 + nl]);
    }
  }
  __syncthreads();
  const int cc = threadIdx.x & 63, nr = threadIdx.x >> 6;
#pragma unroll
  for (int i = 0; i < 16; i++) {
    int n = n0 + nr + 4 * i;
    p.xin[((size_t)b * NL + n) * 512 + c0 + cc] = lds[(nr + 4 * i) * 65 + cc];
  }
  __syncthreads();
}

// ---------------------------------------------------------------------------
// attn unit: 4 queries (one per wave).
// ---------------------------------------------------------------------------
__device__ __forceinline__ void attn_unit(const Params& p, int ublk, Smem& sm) {
  const int lane = threadIdx.x & 63;
  const int wav  = threadIdx.x >> 6;
  const int qidx = ublk * 4 + wav;
  const int b = qidx >> 12;
  const int n = qidx & (NL - 1);
  const int qy = n >> 6, qx = n & 63;

  const float* qp = p.q_t + (size_t)qidx * 16;
  float qreg[16];
#pragma unroll
  for (int i = 0; i < 16; i += 4) {
    float4 t = *(const float4*)(qp + i);
    qreg[i] = t.x; qreg[i + 1] = t.y; qreg[i + 2] = t.z; qreg[i + 3] = t.w;
  }

  const int pt = lane >> 1;
  const int h = lane & 1;
  float2 dxy = *(const float2*)(p.off_t + (size_t)qidx * 64 + 2 * pt);
  float sx = (float)qx + dxy.x;
  float sy = (float)qy + dxy.y;
  float x0f = floorf(sx), y0f = floorf(sy);
  float wx = sx - x0f, wy = sy - y0f;
  int x0i = (int)x0f, y0i = (int)y0f;
  int x0 = min(63, max(0, x0i)), x1 = min(63, max(0, x0i + 1));
  int y0 = min(63, max(0, y0i)), y1 = min(63, max(0, y0i + 1));

  int   yr  = h ? y1 : y0;
  float wyr = h ? wy : (1.f - wy);
  int   pa = yr * 64 + x0, pb = yr * 64 + x1;
  float wa = wyr * (1.f - wx), wb = wyr * wx;

  const float* kb = p.k_t + (size_t)b * NL * 16;
  float da = 0.f, db = 0.f;
  {
    const float* ka = kb + (size_t)pa * 16;
    const float* kc = kb + (size_t)pb * 16;
#pragma unroll
    for (int i = 0; i < 16; i += 4) {
      float4 a4 = *(const float4*)(ka + i);
      float4 c4 = *(const float4*)(kc + i);
      da = fmaf(qreg[i], a4.x, da); da = fmaf(qreg[i + 1], a4.y, da);
      da = fmaf(qreg[i + 2], a4.z, da); da = fmaf(qreg[i + 3], a4.w, da);
      db = fmaf(qreg[i], c4.x, db); db = fmaf(qreg[i + 1], c4.y, db);
      db = fmaf(qreg[i + 2], c4.z, db); db = fmaf(qreg[i + 3], c4.w, db);
    }
  }
  float part = wa * da + wb * db;
  part += __shfl_xor(part, 1, 64);
  float logit = part * 0.25f;

  float m = logit;
#pragma unroll
  for (int s = 32; s > 0; s >>= 1) m = fmaxf(m, __shfl_xor(m, s, 64));
  float e = __expf(logit - m);
  float ssum = e;
#pragma unroll
  for (int s = 32; s > 0; s >>= 1) ssum += __shfl_xor(ssum, s, 64);
  float a = e * 2.f / ssum;     // ssum double-counts each point

  sm.at.w[wav][pt][2 * h + 0] = a * wa;
  sm.at.w[wav][pt][2 * h + 1] = a * wb;
  sm.at.i[wav][pt][2 * h + 0] = pa;
  sm.at.i[wav][pt][2 * h + 1] = pb;
  __syncthreads();

  const short* vb = p.v_t + (size_t)b * NL * 128;
  const int c = 2 * lane;
  float o0 = 0.f, o1 = 0.f;
  for (int pp = 0; pp < 32; pp++) {
#pragma unroll
    for (int t = 0; t < 4; t++) {
      float w  = sm.at.w[wav][pp][t];
      int  pix = sm.at.i[wav][pp][t];
      unsigned int u = *(const unsigned int*)(vb + (size_t)pix * 128 + c);
      o0 = fmaf(w, bfbits2f(u & 0xffffu), o0);
      o1 = fmaf(w, bfbits2f(u >> 16), o1);
    }
  }
  unsigned int pk = (unsigned int)f2bf(o0) | ((unsigned int)f2bf(o1) << 16);
  *(unsigned int*)(p.attn_t + (size_t)qidx * 128 + c) = pk;
  __syncthreads();
}

// ---------------------------------------------------------------------------
// One kernel = whole pipeline. 512 blocks x 256 threads, 2 blocks/CU
// guaranteed by __launch_bounds__(256,2) -> all co-resident for the barrier.
// ---------------------------------------------------------------------------
__global__ __launch_bounds__(256, 2) void fused_k(Params p) {
  const int blk = blockIdx.x;        // 0..511
  const int tid = threadIdx.x;
  __shared__ Smem sm;

  // ---- stage P: weight convert + prep (upsample/copy -> xin) -------------
  {
    for (int i = blk * 256 + tid; i < 225280; i += NBLK * 256) {
      const float* src; int off;
      if      (i <  65536) { src = p.W1;   off = 0; }
      else if (i <  98304) { src = p.W2;   off = 65536; }
      else if (i < 100352) { src = p.Wq;   off = 98304; }
      else if (i < 102400) { src = p.Wk;   off = 100352; }
      else if (i < 118784) { src = p.Wv;   off = 102400; }
      else if (i < 126976) { src = p.Woff; off = 118784; }
      else                 { src = p.Wb;   off = 126976; }
      p.wc[i] = (short)f2bf(src[i - off]);
    }
#pragma unroll
    for (int j = 0; j < 2; j++) {
      int u = blk * 2 + j;           // 1024 units: (64 nx, 8 cy, 2 b)
      prep_unit(p, u & 63, (u >> 6) & 7, u >> 9, sm.prep);
    }
  }
  grid_barrier(p.bar);

  // ---- stage A: qf = W1@xin(512), vf = W2@xin(:256) ----------------------
#pragma unroll
  for (int j = 0; j < 2; j++) {
    int u = blk * 2 + j;             // 1024 units: (128 bx, 4 by, 2 z)
    int ax = u & 127, ay = (u >> 7) & 3, az = u >> 9;
    if (az == 0)
      gemm_core<128, 512, 0, 2, 0>(p.wc, p.b1, p.xin, 512, nullptr, 0, p.qf,
                                   nullptr, nullptr, nullptr, nullptr, ax, ay);
    else
      gemm_core<128, 256, 0, 2, 0>(p.wc + 65536, p.b2, p.xin, 512, nullptr, 0,
                                   p.vf, nullptr, nullptr, nullptr, nullptr, ax, ay);
  }
  grid_barrier(p.bar);

  // ---- stage B: q, k, off, v ---------------------------------------------
#pragma unroll
  for (int j = 0; j < 2; j++) {
    int u = blk * 2 + j;             // 1024 units
    if (u < 128)
      gemm_core<16, 128, 0, 1, 1>(p.wc + 98304, p.bq, p.qf, 128, nullptr, 0,
                                  p.q_t, nullptr, nullptr, nullptr, nullptr, u, 0);
    else if (u < 256)
      gemm_core<16, 128, 0, 1, 1>(p.wc + 100352, p.bk, p.vf, 128, nullptr, 0,
                                  p.k_t, nullptr, nullptr, nullptr, nullptr, u - 128, 0);
    else if (u < 512)
      gemm_core<64, 128, 0, 2, 1>(p.wc + 118784, p.boff, p.qf, 128, nullptr, 0,
                                  p.off_t, nullptr, nullptr, nullptr, nullptr,
                                  (u - 256) & 127, (u - 256) >> 7);
    else
      gemm_core<128, 128, 0, 2, 0>(p.wc + 102400, p.bv, p.vf, 128, nullptr, 0,
                                   p.v_t, nullptr, nullptr, nullptr, nullptr,
                                   (u - 512) & 127, (u - 512) >> 7);
  }
  grid_barrier(p.bar);

  // ---- stage T: deformable attention -------------------------------------
#pragma unroll
  for (int j = 0; j < 4; j++)
    attn_unit(p, blk * 4 + j, sm);   // 2048 units
  grid_barrier(p.bar);

  // ---- stage F: out = ReLU(BN(Wb @ [attn; xin_high])) --------------------
#pragma unroll
  for (int j = 0; j < 2; j++) {
    int u = blk * 2 + j;             // 1024 units: (128 bx, 8 by)
    gemm_core<256, 128, 256, 2, 2>(p.wc + 126976, nullptr, p.attn_t, 128,
                                   p.xin, 512, p.out,
                                   p.gamma, p.beta, p.rmean, p.rvar,
                                   u & 127, u >> 7);
  }
}

// ---------------------------------------------------------------------------
extern "C" void kernel_launch(void* const* d_in, const int* in_sizes, int n_in,
                              void* d_out, int out_size, void* d_ws, size_t ws_size,
                              hipStream_t stream) {
  Params p;
  p.low   = (const float*)d_in[0];
  p.high  = (const float*)d_in[1];
  p.W1    = (const float*)d_in[2];
  p.b1    = (const float*)d_in[3];
  p.W2    = (const float*)d_in[4];
  p.b2    = (const float*)d_in[5];
  p.Wq    = (const float*)d_in[6];
  p.bq    = (const float*)d_in[7];
  p.Wk    = (const float*)d_in[8];
  p.bk    = (const float*)d_in[9];
  p.Wv    = (const float*)d_in[10];
  p.bv    = (const float*)d_in[11];
  p.Woff  = (const float*)d_in[12];
  p.boff  = (const float*)d_in[13];
  p.Wb    = (const float*)d_in[14];
  p.gamma = (const float*)d_in[15];
  p.beta  = (const float*)d_in[16];
  p.rmean = (const float*)d_in[17];
  p.rvar  = (const float*)d_in[18];
  p.out   = (float*)d_out;

  short* ws = (short*)d_ws;
  p.xin    = ws;                     // [2][4096][512]  bf16
  p.qf     = p.xin + 4194304;        // [2][4096][128]
  p.vf     = p.qf + 1048576;         // [2][4096][128]
  p.v_t    = p.vf + 1048576;         // [2][4096][128]
  p.attn_t = p.v_t + 1048576;        // [2][4096][128]
  p.wc     = p.attn_t + 1048576;     // 225,280 bf16
  p.q_t    = (float*)(p.wc + 225280);// [2][4096][16] f32
  p.k_t    = p.q_t + 131072;
  p.off_t  = p.k_t + 131072;         // [2][4096][64] f32
  p.bar    = (unsigned*)((char*)d_ws + (32u << 20));  // well past ~20.4MB used

  // zero the barrier cells (graph-capturable async memset)
  hipMemsetAsync(p.bar, 0, 256, stream);
  fused_k<<<NBLK, 256, 0, stream>>>(p);
}

// Round 6
// 160.664 us; speedup vs baseline: 3.3032x; 3.3032x over previous
//
#include <hip/hip_runtime.h>
#include <hip/hip_bf16.h>

#define NL 4096   // 64*64 low-res pixels
#define HH 32
#define WH 32

typedef __attribute__((ext_vector_type(8))) short s8v;   // 8 bf16 MFMA A/B frag
typedef __attribute__((ext_vector_type(4))) short s4v;   // 4 bf16 (8B)
typedef __attribute__((ext_vector_type(4))) float f32x4; // MFMA C/D frag

static __device__ inline unsigned short f2bf(float x) {
  __hip_bfloat16 h = __float2bfloat16(x);   // RNE
  return *reinterpret_cast<unsigned short*>(&h);
}
static __device__ inline float bfbits2f(unsigned int lo16) {
  unsigned int u = lo16 << 16;
  return *reinterpret_cast<float*>(&u);
}

// ---------------------------------------------------------------------------
// Weight fp32 -> bf16, packed:
//   [0,65536)        W1   [128][512]
//   [65536,98304)    W2   [128][256]
//   [98304,100352)   Wq   [16][128]   \
//   [100352,108544)  Woff [64][128]    | stage-B concat: 224 rows, K=128
//   [108544,110592)  Wk   [16][128]    |
//   [110592,126976)  Wv   [128][128]  /
//   [126976,225280)  Wb   [256][384]
// ---------------------------------------------------------------------------
__global__ __launch_bounds__(256) void convert_weights_k(
    const float* __restrict__ w1, const float* __restrict__ w2,
    const float* __restrict__ wq, const float* __restrict__ woff,
    const float* __restrict__ wk, const float* __restrict__ wv,
    const float* __restrict__ wb, short* __restrict__ dst) {
  int i = blockIdx.x * 256 + threadIdx.x;
  const float* src; int off;
  if      (i <  65536) { src = w1;   off = 0; }
  else if (i <  98304) { src = w2;   off = 65536; }
  else if (i < 100352) { src = wq;   off = 98304; }
  else if (i < 108544) { src = woff; off = 100352; }
  else if (i < 110592) { src = wk;   off = 108544; }
  else if (i < 126976) { src = wv;   off = 110592; }
  else if (i < 225280) { src = wb;   off = 126976; }
  else return;
  dst[i] = (short)f2bf(src[i - off]);
}

// ---------------------------------------------------------------------------
// K1: fused prep + stageA + stageB, per-pixel dependencies only.
// 512 blocks x 256 thr; block handles 16 pixels end-to-end.
//   P : upsample(high)+copy(low) -> xin LDS tile [16][520] bf16; store xh
//   A1: qf = W1 @ xin (K=512)  -> LDS [16][136] bf16
//   A2: vf = W2 @ xin (K=256)  -> LDS [16][136] bf16
//   B : q,off (from qf) / k,v (from vf), 14 m-frags over 4 waves
// ---------------------------------------------------------------------------
__global__ __launch_bounds__(256) void k1_fused(
    const float* __restrict__ low, const float* __restrict__ high,
    const short* __restrict__ wc,
    const float* __restrict__ b1, const float* __restrict__ b2,
    const float* __restrict__ bq, const float* __restrict__ boff,
    const float* __restrict__ bk, const float* __restrict__ bv,
    short* __restrict__ xh, float* __restrict__ q_t, float* __restrict__ k_t,
    float* __restrict__ off_t, short* __restrict__ v_t) {
  __shared__ short xin_s[16 * 520];   // stride 520 sh = 1040B (16B-aligned)
  __shared__ short qf_s[16 * 136];    // stride 136 sh = 272B
  __shared__ short vf_s[16 * 136];
  const int tid = threadIdx.x;
  const int pix0 = blockIdx.x * 16;
  const int b = pix0 >> 12;
  const int n0 = pix0 & (NL - 1);

  // ---- phase P: build xin tile ----
  {
    const int nl = tid & 15, cg = tid >> 4;   // px-in-tile, channel group
    const int n = n0 + nl;
    const int y = n >> 6, x = n & 63;
    float sx = x * 0.5f - 0.25f;
    float sy = y * 0.5f - 0.25f;
    float x0f = floorf(sx), y0f = floorf(sy);
    float wx = sx - x0f, wy = sy - y0f;
    int x0i = (int)x0f, y0i = (int)y0f;
    int x0c = min(WH - 1, max(0, x0i)), x1c = min(WH - 1, max(0, x0i + 1));
    int y0c = min(HH - 1, max(0, y0i)), y1c = min(HH - 1, max(0, y0i + 1));
    float w00 = (1.f - wy) * (1.f - wx), w01 = (1.f - wy) * wx;
    float w10 = wy * (1.f - wx),         w11 = wy * wx;
#pragma unroll
    for (int i = 0; i < 16; i++) {
      int c = cg * 16 + i;
      const float* f = high + (size_t)(b * 256 + c) * (HH * WH);
      float v = w00 * f[y0c * WH + x0c] + w01 * f[y0c * WH + x1c]
              + w10 * f[y1c * WH + x0c] + w11 * f[y1c * WH + x1c];
      xin_s[nl * 520 + c] = (short)f2bf(v);
      xin_s[nl * 520 + 256 + c] =
          (short)f2bf(low[(size_t)(b * 256 + c) * NL + n]);
    }
  }
  __syncthreads();

  // ---- store xh (high half of xin, needed by final GEMM) ----
  {
    const int r = tid >> 4, c0 = (tid & 15) * 16;
    s8v v0 = *(const s8v*)(xin_s + r * 520 + c0);
    s8v v1 = *(const s8v*)(xin_s + r * 520 + c0 + 8);
    *(s8v*)(xh + (size_t)(pix0 + r) * 256 + c0) = v0;
    *(s8v*)(xh + (size_t)(pix0 + r) * 256 + c0 + 8) = v1;
  }

  const int wave = tid >> 6, lane = tid & 63;
  const int quad = lane >> 4, id = lane & 15;

  // ---- phase A1: qf = W1 @ xin, M=128 K=512 (wave: 32 m-rows) ----
  {
    f32x4 acc0 = (f32x4){0.f, 0.f, 0.f, 0.f};
    f32x4 acc1 = (f32x4){0.f, 0.f, 0.f, 0.f};
    const short* a0 = wc + (size_t)(wave * 32 + id) * 512 + quad * 8;
    const short* a1 = a0 + 16 * 512;
    const short* bp = xin_s + id * 520 + quad * 8;
#pragma unroll
    for (int kk = 0; kk < 512; kk += 32) {
      s8v bf = *(const s8v*)(bp + kk);
      acc0 = __builtin_amdgcn_mfma_f32_16x16x32_bf16(*(const s8v*)(a0 + kk), bf, acc0, 0, 0, 0);
      acc1 = __builtin_amdgcn_mfma_f32_16x16x32_bf16(*(const s8v*)(a1 + kk), bf, acc1, 0, 0, 0);
    }
    int m0 = wave * 32 + quad * 4;
    s4v o0, o1;
#pragma unroll
    for (int r = 0; r < 4; r++) {
      o0[r] = (short)f2bf(acc0[r] + b1[m0 + r]);
      o1[r] = (short)f2bf(acc1[r] + b1[m0 + 16 + r]);
    }
    *(s4v*)(qf_s + id * 136 + m0) = o0;
    *(s4v*)(qf_s + id * 136 + m0 + 16) = o1;
  }

  // ---- phase A2: vf = W2 @ xin[:,0:256], M=128 K=256 ----
  {
    f32x4 acc0 = (f32x4){0.f, 0.f, 0.f, 0.f};
    f32x4 acc1 = (f32x4){0.f, 0.f, 0.f, 0.f};
    const short* a0 = wc + 65536 + (size_t)(wave * 32 + id) * 256 + quad * 8;
    const short* a1 = a0 + 16 * 256;
    const short* bp = xin_s + id * 520 + quad * 8;
#pragma unroll
    for (int kk = 0; kk < 256; kk += 32) {
      s8v bf = *(const s8v*)(bp + kk);
      acc0 = __builtin_amdgcn_mfma_f32_16x16x32_bf16(*(const s8v*)(a0 + kk), bf, acc0, 0, 0, 0);
      acc1 = __builtin_amdgcn_mfma_f32_16x16x32_bf16(*(const s8v*)(a1 + kk), bf, acc1, 0, 0, 0);
    }
    int m0 = wave * 32 + quad * 4;
    s4v o0, o1;
#pragma unroll
    for (int r = 0; r < 4; r++) {
      o0[r] = (short)f2bf(acc0[r] + b2[m0 + r]);
      o1[r] = (short)f2bf(acc1[r] + b2[m0 + 16 + r]);
    }
    *(s4v*)(vf_s + id * 136 + m0) = o0;
    *(s4v*)(vf_s + id * 136 + m0 + 16) = o1;
  }
  __syncthreads();

  // ---- phase B: 14 m-frags (0:q, 1-4:off, 5:k, 6-13:v), K=128 ----
  for (int f = wave; f < 14; f += 4) {
    const short* ap = wc + 98304 + (size_t)(f * 16 + id) * 128 + quad * 8;
    const short* bp = (f < 5 ? qf_s : vf_s) + id * 136 + quad * 8;
    f32x4 acc = (f32x4){0.f, 0.f, 0.f, 0.f};
#pragma unroll
    for (int kk = 0; kk < 128; kk += 32)
      acc = __builtin_amdgcn_mfma_f32_16x16x32_bf16(
          *(const s8v*)(ap + kk), *(const s8v*)(bp + kk), acc, 0, 0, 0);
    const int pix = pix0 + id;
    const int mq = quad * 4;
    if (f == 0) {
      f32x4 v;
#pragma unroll
      for (int r = 0; r < 4; r++) v[r] = acc[r] + bq[mq + r];
      *(f32x4*)(q_t + (size_t)pix * 16 + mq) = v;
    } else if (f < 5) {
      int m = (f - 1) * 16 + mq;
      f32x4 v;
#pragma unroll
      for (int r = 0; r < 4; r++) v[r] = acc[r] + boff[m + r];
      *(f32x4*)(off_t + (size_t)pix * 64 + m) = v;
    } else if (f == 5) {
      f32x4 v;
#pragma unroll
      for (int r = 0; r < 4; r++) v[r] = acc[r] + bk[mq + r];
      *(f32x4*)(k_t + (size_t)pix * 16 + mq) = v;
    } else {
      int m = (f - 6) * 16 + mq;
      s4v o;
#pragma unroll
      for (int r = 0; r < 4; r++) o[r] = (short)f2bf(acc[r] + bv[m + r]);
      *(s4v*)(v_t + (size_t)pix * 128 + m) = o;
    }
  }
}

// ---------------------------------------------------------------------------
// K3 GEMM core (MODE 2 path): out = ReLU(BN(W @ [B1;B2])), channel-major.
// ---------------------------------------------------------------------------
template <int M, int K1, int K2, int MF>
__global__ __launch_bounds__(256) void finalg_k(
    const short* __restrict__ W,
    const short* __restrict__ B1, int sB1,
    const short* __restrict__ B2, int sB2,
    float* __restrict__ Y,
    const float* __restrict__ gamma, const float* __restrict__ beta,
    const float* __restrict__ rmean, const float* __restrict__ rvar) {
  constexpr int K = K1 + K2;
  const int tid = threadIdx.x;
  const int wave = tid >> 6, lane = tid & 63;
  const int quad = lane >> 4, id = lane & 15;
  const int n = blockIdx.x * 64 + wave * 16 + id;
  const int m0 = blockIdx.y * (MF * 16);

  f32x4 acc[MF];
#pragma unroll
  for (int mf = 0; mf < MF; mf++) acc[mf] = (f32x4){0.f, 0.f, 0.f, 0.f};

  const short* ap[MF];
#pragma unroll
  for (int mf = 0; mf < MF; mf++)
    ap[mf] = W + (size_t)(m0 + mf * 16 + id) * K + quad * 8;
  const short* bp = B1 + (size_t)n * sB1 + quad * 8;
#pragma unroll
  for (int kk = 0; kk < K1; kk += 32) {
    s8v bf = *(const s8v*)(bp + kk);
#pragma unroll
    for (int mf = 0; mf < MF; mf++)
      acc[mf] = __builtin_amdgcn_mfma_f32_16x16x32_bf16(
          *(const s8v*)(ap[mf] + kk), bf, acc[mf], 0, 0, 0);
  }
  const short* bp2 = B2 + (size_t)n * sB2 + quad * 8;
#pragma unroll
  for (int kk = 0; kk < K2; kk += 32) {
    s8v bf = *(const s8v*)(bp2 + kk);
#pragma unroll
    for (int mf = 0; mf < MF; mf++)
      acc[mf] = __builtin_amdgcn_mfma_f32_16x16x32_bf16(
          *(const s8v*)(ap[mf] + K1 + kk), bf, acc[mf], 0, 0, 0);
  }

  const int bb = n >> 12, nlow = n & (NL - 1);
#pragma unroll
  for (int mf = 0; mf < MF; mf++) {
    int mbase = m0 + mf * 16 + quad * 4;
#pragma unroll
    for (int r = 0; r < 4; r++) {
      int o = mbase + r;
      float s  = gamma[o] * rsqrtf(rvar[o] + 1e-5f);
      float sh = beta[o] - rmean[o] * s;
      Y[((size_t)bb * M + o) * NL + nlow] = fmaxf(fmaf(acc[mf][r], s, sh), 0.f);
    }
  }
}

// ---------------------------------------------------------------------------
// K2: deformable attention. One wave per query; per-wave LDS tables, no sync.
// ---------------------------------------------------------------------------
__global__ __launch_bounds__(256) void attn_k(
    const float* __restrict__ q_t, const float* __restrict__ k_t,
    const short* __restrict__ v_t, const float* __restrict__ off_t,
    short* __restrict__ out) {
  const int lane = threadIdx.x;                // 0..63
  const int wav  = threadIdx.y;                // 0..3
  const int qidx = blockIdx.x * 4 + wav;
  const int b = qidx >> 12;
  const int n = qidx & (NL - 1);
  const int qy = n >> 6, qx = n & 63;

  __shared__ float s_w[4][32][4];
  __shared__ int   s_i[4][32][4];

  const float* qp = q_t + (size_t)qidx * 16;
  float qreg[16];
#pragma unroll
  for (int i = 0; i < 16; i += 4) {
    float4 t = *(const float4*)(qp + i);
    qreg[i] = t.x; qreg[i + 1] = t.y; qreg[i + 2] = t.z; qreg[i + 3] = t.w;
  }

  const int pt = lane >> 1;
  const int h = lane & 1;
  float2 dxy = *(const float2*)(off_t + (size_t)qidx * 64 + 2 * pt);
  float sx = (float)qx + dxy.x;
  float sy = (float)qy + dxy.y;
  float x0f = floorf(sx), y0f = floorf(sy);
  float wx = sx - x0f, wy = sy - y0f;
  int x0i = (int)x0f, y0i = (int)y0f;
  int x0 = min(63, max(0, x0i)), x1 = min(63, max(0, x0i + 1));
  int y0 = min(63, max(0, y0i)), y1 = min(63, max(0, y0i + 1));

  int   yr  = h ? y1 : y0;
  float wyr = h ? wy : (1.f - wy);
  int   pa = yr * 64 + x0, pb = yr * 64 + x1;
  float wa = wyr * (1.f - wx), wb = wyr * wx;

  const float* kb = k_t + (size_t)b * NL * 16;
  float da = 0.f, db = 0.f;
  {
    const float* ka = kb + (size_t)pa * 16;
    const float* kc = kb + (size_t)pb * 16;
#pragma unroll
    for (int i = 0; i < 16; i += 4) {
      float4 a4 = *(const float4*)(ka + i);
      float4 c4 = *(const float4*)(kc + i);
      da = fmaf(qreg[i], a4.x, da); da = fmaf(qreg[i + 1], a4.y, da);
      da = fmaf(qreg[i + 2], a4.z, da); da = fmaf(qreg[i + 3], a4.w, da);
      db = fmaf(qreg[i], c4.x, db); db = fmaf(qreg[i + 1], c4.y, db);
      db = fmaf(qreg[i + 2], c4.z, db); db = fmaf(qreg[i + 3], c4.w, db);
    }
  }
  float part = wa * da + wb * db;
  part += __shfl_xor(part, 1, 64);
  float logit = part * 0.25f;

  float m = logit;
#pragma unroll
  for (int s = 32; s > 0; s >>= 1) m = fmaxf(m, __shfl_xor(m, s, 64));
  float e = __expf(logit - m);
  float ssum = e;
#pragma unroll
  for (int s = 32; s > 0; s >>= 1) ssum += __shfl_xor(ssum, s, 64);
  float a = e * 2.f / ssum;     // ssum double-counts each point

  // per-wave tables; same-wave LDS RAW is lgkmcnt-ordered -> no barrier
  s_w[wav][pt][2 * h + 0] = a * wa;
  s_w[wav][pt][2 * h + 1] = a * wb;
  s_i[wav][pt][2 * h + 0] = pa;
  s_i[wav][pt][2 * h + 1] = pb;

  const short* vb = v_t + (size_t)b * NL * 128;
  const int c = 2 * lane;
  float o0 = 0.f, o1 = 0.f;
  for (int pp = 0; pp < 32; pp++) {
#pragma unroll
    for (int t = 0; t < 4; t++) {
      float w  = s_w[wav][pp][t];
      int  pix = s_i[wav][pp][t];
      unsigned int u = *(const unsigned int*)(vb + (size_t)pix * 128 + c);
      o0 = fmaf(w, bfbits2f(u & 0xffffu), o0);
      o1 = fmaf(w, bfbits2f(u >> 16), o1);
    }
  }
  unsigned int pk = (unsigned int)f2bf(o0) | ((unsigned int)f2bf(o1) << 16);
  *(unsigned int*)(out + (size_t)qidx * 128 + c) = pk;
}

// ---------------------------------------------------------------------------
extern "C" void kernel_launch(void* const* d_in, const int* in_sizes, int n_in,
                              void* d_out, int out_size, void* d_ws, size_t ws_size,
                              hipStream_t stream) {
  const float* low   = (const float*)d_in[0];
  const float* high  = (const float*)d_in[1];
  const float* W1    = (const float*)d_in[2];
  const float* b1    = (const float*)d_in[3];
  const float* W2    = (const float*)d_in[4];
  const float* b2    = (const float*)d_in[5];
  const float* Wq    = (const float*)d_in[6];
  const float* bq    = (const float*)d_in[7];
  const float* Wk    = (const float*)d_in[8];
  const float* bk    = (const float*)d_in[9];
  const float* Wv    = (const float*)d_in[10];
  const float* bv    = (const float*)d_in[11];
  const float* Woff  = (const float*)d_in[12];
  const float* boff  = (const float*)d_in[13];
  const float* Wb    = (const float*)d_in[14];
  const float* gamma = (const float*)d_in[15];
  const float* beta  = (const float*)d_in[16];
  const float* rmean = (const float*)d_in[17];
  const float* rvar  = (const float*)d_in[18];
  float* out = (float*)d_out;

  short* ws    = (short*)d_ws;
  short* xh    = ws;                    // [8192][256] bf16 = 2,097,152 sh
  short* v_t   = xh + 2097152;          // [8192][128] bf16
  short* attn_t= v_t + 1048576;         // [8192][128] bf16
  short* wc    = attn_t + 1048576;      // 225,280 bf16
  float* q_t   = (float*)(wc + 225280); // [8192][16] f32
  float* k_t   = q_t + 131072;          // [8192][16] f32
  float* off_t = k_t + 131072;          // [8192][64] f32

  convert_weights_k<<<880, 256, 0, stream>>>(W1, W2, Wq, Woff, Wk, Wv, Wb, wc);
  k1_fused<<<512, 256, 0, stream>>>(low, high, wc, b1, b2, bq, boff, bk, bv,
                                    xh, q_t, k_t, off_t, v_t);
  attn_k<<<2048, dim3(64, 4), 0, stream>>>(q_t, k_t, v_t, off_t, attn_t);
  finalg_k<256, 128, 256, 2><<<dim3(128, 8), 256, 0, stream>>>(
      wc + 126976, attn_t, 128, xh, 256, out, gamma, beta, rmean, rvar);
}

// Round 7
// 160.409 us; speedup vs baseline: 3.3085x; 1.0016x over previous
//
#include <hip/hip_runtime.h>
#include <hip/hip_bf16.h>

#define NL 4096   // 64*64 low-res pixels
#define HH 32
#define WH 32

typedef __attribute__((ext_vector_type(8))) short s8v;   // 8 bf16 MFMA A/B frag
typedef __attribute__((ext_vector_type(4))) short s4v;   // 4 bf16 (8B)
typedef __attribute__((ext_vector_type(4))) float f32x4; // MFMA C/D frag

static __device__ inline unsigned short f2bf(float x) {
  __hip_bfloat16 h = __float2bfloat16(x);   // RNE
  return *reinterpret_cast<unsigned short*>(&h);
}
static __device__ inline float bfbits2f(unsigned int lo16) {
  unsigned int u = lo16 << 16;
  return *reinterpret_cast<float*>(&u);
}

// ---------------------------------------------------------------------------
// Weight fp32 -> bf16, packed:
//   [0,65536)        W1   [128][512]
//   [65536,98304)    W2   [128][256]
//   [98304,100352)   Wq   [16][128]   \
//   [100352,108544)  Woff [64][128]    | stage-B concat: 224 rows, K=128
//   [108544,110592)  Wk   [16][128]    |
//   [110592,126976)  Wv   [128][128]  /
//   [126976,225280)  Wb   [256][384]
// ---------------------------------------------------------------------------
__global__ __launch_bounds__(256) void convert_weights_k(
    const float* __restrict__ w1, const float* __restrict__ w2,
    const float* __restrict__ wq, const float* __restrict__ woff,
    const float* __restrict__ wk, const float* __restrict__ wv,
    const float* __restrict__ wb, short* __restrict__ dst) {
  int i = blockIdx.x * 256 + threadIdx.x;
  const float* src; int off;
  if      (i <  65536) { src = w1;   off = 0; }
  else if (i <  98304) { src = w2;   off = 65536; }
  else if (i < 100352) { src = wq;   off = 98304; }
  else if (i < 108544) { src = woff; off = 100352; }
  else if (i < 110592) { src = wk;   off = 108544; }
  else if (i < 126976) { src = wv;   off = 110592; }
  else if (i < 225280) { src = wb;   off = 126976; }
  else return;
  dst[i] = (short)f2bf(src[i - off]);
}

// ---------------------------------------------------------------------------
// K1: fused prep + stageA + stageB (unchanged from round 6).
// 512 blocks x 256 thr; block handles 16 pixels end-to-end.
// ---------------------------------------------------------------------------
__global__ __launch_bounds__(256) void k1_fused(
    const float* __restrict__ low, const float* __restrict__ high,
    const short* __restrict__ wc,
    const float* __restrict__ b1, const float* __restrict__ b2,
    const float* __restrict__ bq, const float* __restrict__ boff,
    const float* __restrict__ bk, const float* __restrict__ bv,
    short* __restrict__ xh, float* __restrict__ q_t, float* __restrict__ k_t,
    float* __restrict__ off_t, short* __restrict__ v_t) {
  __shared__ short xin_s[16 * 520];
  __shared__ short qf_s[16 * 136];
  __shared__ short vf_s[16 * 136];
  const int tid = threadIdx.x;
  const int pix0 = blockIdx.x * 16;
  const int b = pix0 >> 12;
  const int n0 = pix0 & (NL - 1);

  // ---- phase P: build xin tile ----
  {
    const int nl = tid & 15, cg = tid >> 4;
    const int n = n0 + nl;
    const int y = n >> 6, x = n & 63;
    float sx = x * 0.5f - 0.25f;
    float sy = y * 0.5f - 0.25f;
    float x0f = floorf(sx), y0f = floorf(sy);
    float wx = sx - x0f, wy = sy - y0f;
    int x0i = (int)x0f, y0i = (int)y0f;
    int x0c = min(WH - 1, max(0, x0i)), x1c = min(WH - 1, max(0, x0i + 1));
    int y0c = min(HH - 1, max(0, y0i)), y1c = min(HH - 1, max(0, y0i + 1));
    float w00 = (1.f - wy) * (1.f - wx), w01 = (1.f - wy) * wx;
    float w10 = wy * (1.f - wx),         w11 = wy * wx;
#pragma unroll
    for (int i = 0; i < 16; i++) {
      int c = cg * 16 + i;
      const float* f = high + (size_t)(b * 256 + c) * (HH * WH);
      float v = w00 * f[y0c * WH + x0c] + w01 * f[y0c * WH + x1c]
              + w10 * f[y1c * WH + x0c] + w11 * f[y1c * WH + x1c];
      xin_s[nl * 520 + c] = (short)f2bf(v);
      xin_s[nl * 520 + 256 + c] =
          (short)f2bf(low[(size_t)(b * 256 + c) * NL + n]);
    }
  }
  __syncthreads();

  // ---- store xh (high half of xin, needed by K2 final GEMM) ----
  {
    const int r = tid >> 4, c0 = (tid & 15) * 16;
    s8v v0 = *(const s8v*)(xin_s + r * 520 + c0);
    s8v v1 = *(const s8v*)(xin_s + r * 520 + c0 + 8);
    *(s8v*)(xh + (size_t)(pix0 + r) * 256 + c0) = v0;
    *(s8v*)(xh + (size_t)(pix0 + r) * 256 + c0 + 8) = v1;
  }

  const int wave = tid >> 6, lane = tid & 63;
  const int quad = lane >> 4, id = lane & 15;

  // ---- phase A1: qf = W1 @ xin, M=128 K=512 ----
  {
    f32x4 acc0 = (f32x4){0.f, 0.f, 0.f, 0.f};
    f32x4 acc1 = (f32x4){0.f, 0.f, 0.f, 0.f};
    const short* a0 = wc + (size_t)(wave * 32 + id) * 512 + quad * 8;
    const short* a1 = a0 + 16 * 512;
    const short* bp = xin_s + id * 520 + quad * 8;
#pragma unroll
    for (int kk = 0; kk < 512; kk += 32) {
      s8v bf = *(const s8v*)(bp + kk);
      acc0 = __builtin_amdgcn_mfma_f32_16x16x32_bf16(*(const s8v*)(a0 + kk), bf, acc0, 0, 0, 0);
      acc1 = __builtin_amdgcn_mfma_f32_16x16x32_bf16(*(const s8v*)(a1 + kk), bf, acc1, 0, 0, 0);
    }
    int m0 = wave * 32 + quad * 4;
    s4v o0, o1;
#pragma unroll
    for (int r = 0; r < 4; r++) {
      o0[r] = (short)f2bf(acc0[r] + b1[m0 + r]);
      o1[r] = (short)f2bf(acc1[r] + b1[m0 + 16 + r]);
    }
    *(s4v*)(qf_s + id * 136 + m0) = o0;
    *(s4v*)(qf_s + id * 136 + m0 + 16) = o1;
  }

  // ---- phase A2: vf = W2 @ xin[:,0:256], M=128 K=256 ----
  {
    f32x4 acc0 = (f32x4){0.f, 0.f, 0.f, 0.f};
    f32x4 acc1 = (f32x4){0.f, 0.f, 0.f, 0.f};
    const short* a0 = wc + 65536 + (size_t)(wave * 32 + id) * 256 + quad * 8;
    const short* a1 = a0 + 16 * 256;
    const short* bp = xin_s + id * 520 + quad * 8;
#pragma unroll
    for (int kk = 0; kk < 256; kk += 32) {
      s8v bf = *(const s8v*)(bp + kk);
      acc0 = __builtin_amdgcn_mfma_f32_16x16x32_bf16(*(const s8v*)(a0 + kk), bf, acc0, 0, 0, 0);
      acc1 = __builtin_amdgcn_mfma_f32_16x16x32_bf16(*(const s8v*)(a1 + kk), bf, acc1, 0, 0, 0);
    }
    int m0 = wave * 32 + quad * 4;
    s4v o0, o1;
#pragma unroll
    for (int r = 0; r < 4; r++) {
      o0[r] = (short)f2bf(acc0[r] + b2[m0 + r]);
      o1[r] = (short)f2bf(acc1[r] + b2[m0 + 16 + r]);
    }
    *(s4v*)(vf_s + id * 136 + m0) = o0;
    *(s4v*)(vf_s + id * 136 + m0 + 16) = o1;
  }
  __syncthreads();

  // ---- phase B: 14 m-frags (0:q, 1-4:off, 5:k, 6-13:v), K=128 ----
  for (int f = wave; f < 14; f += 4) {
    const short* ap = wc + 98304 + (size_t)(f * 16 + id) * 128 + quad * 8;
    const short* bp = (f < 5 ? qf_s : vf_s) + id * 136 + quad * 8;
    f32x4 acc = (f32x4){0.f, 0.f, 0.f, 0.f};
#pragma unroll
    for (int kk = 0; kk < 128; kk += 32)
      acc = __builtin_amdgcn_mfma_f32_16x16x32_bf16(
          *(const s8v*)(ap + kk), *(const s8v*)(bp + kk), acc, 0, 0, 0);
    const int pix = pix0 + id;
    const int mq = quad * 4;
    if (f == 0) {
      f32x4 v;
#pragma unroll
      for (int r = 0; r < 4; r++) v[r] = acc[r] + bq[mq + r];
      *(f32x4*)(q_t + (size_t)pix * 16 + mq) = v;
    } else if (f < 5) {
      int m = (f - 1) * 16 + mq;
      f32x4 v;
#pragma unroll
      for (int r = 0; r < 4; r++) v[r] = acc[r] + boff[m + r];
      *(f32x4*)(off_t + (size_t)pix * 64 + m) = v;
    } else if (f == 5) {
      f32x4 v;
#pragma unroll
      for (int r = 0; r < 4; r++) v[r] = acc[r] + bk[mq + r];
      *(f32x4*)(k_t + (size_t)pix * 16 + mq) = v;
    } else {
      int m = (f - 6) * 16 + mq;
      s4v o;
#pragma unroll
      for (int r = 0; r < 4; r++) o[r] = (short)f2bf(acc[r] + bv[m + r]);
      *(s4v*)(v_t + (size_t)pix * 128 + m) = o;
    }
  }
}

// ---------------------------------------------------------------------------
// K2: fused deformable attention + final GEMM (+BN+ReLU).
// 512 blocks x 256 thr; block owns 16 pixels.
//   T: each wave runs attention for 4 queries sequentially -> attn_s [16][136]
//   F: out[:,n] = ReLU(BN(Wb @ [attn_s[n]; xh[n]])), M=256 split over 4 waves
// ---------------------------------------------------------------------------
__global__ __launch_bounds__(256) void k2_fused(
    const float* __restrict__ q_t, const float* __restrict__ k_t,
    const short* __restrict__ v_t, const float* __restrict__ off_t,
    const short* __restrict__ xh, const short* __restrict__ wb,
    const float* __restrict__ gamma, const float* __restrict__ beta,
    const float* __restrict__ rmean, const float* __restrict__ rvar,
    float* __restrict__ out) {
  __shared__ float s_w[4][32][4];
  __shared__ int   s_i[4][32][4];
  __shared__ short attn_s[16 * 136];
  const int tid = threadIdx.x;
  const int wave = tid >> 6, lane = tid & 63;
  const int pix0 = blockIdx.x * 16;

  // ---- phase T: attention, 4 queries per wave ----
  const int pt = lane >> 1, h = lane & 1;
  const int c = 2 * lane;
  for (int jj = 0; jj < 4; jj++) {
    const int qidx = pix0 + wave * 4 + jj;
    const int b = qidx >> 12;
    const int n = qidx & (NL - 1);
    const int qy = n >> 6, qx = n & 63;

    const float* qp = q_t + (size_t)qidx * 16;
    float qreg[16];
#pragma unroll
    for (int i = 0; i < 16; i += 4) {
      float4 t = *(const float4*)(qp + i);
      qreg[i] = t.x; qreg[i + 1] = t.y; qreg[i + 2] = t.z; qreg[i + 3] = t.w;
    }

    float2 dxy = *(const float2*)(off_t + (size_t)qidx * 64 + 2 * pt);
    float sx = (float)qx + dxy.x;
    float sy = (float)qy + dxy.y;
    float x0f = floorf(sx), y0f = floorf(sy);
    float wx = sx - x0f, wy = sy - y0f;
    int x0i = (int)x0f, y0i = (int)y0f;
    int x0 = min(63, max(0, x0i)), x1 = min(63, max(0, x0i + 1));
    int y0 = min(63, max(0, y0i)), y1 = min(63, max(0, y0i + 1));

    int   yr  = h ? y1 : y0;
    float wyr = h ? wy : (1.f - wy);
    int   pa = yr * 64 + x0, pb = yr * 64 + x1;
    float wa = wyr * (1.f - wx), wb_ = wyr * wx;

    const float* kb = k_t + (size_t)b * NL * 16;
    float da = 0.f, db = 0.f;
    {
      const float* ka = kb + (size_t)pa * 16;
      const float* kc = kb + (size_t)pb * 16;
#pragma unroll
      for (int i = 0; i < 16; i += 4) {
        float4 a4 = *(const float4*)(ka + i);
        float4 c4 = *(const float4*)(kc + i);
        da = fmaf(qreg[i], a4.x, da); da = fmaf(qreg[i + 1], a4.y, da);
        da = fmaf(qreg[i + 2], a4.z, da); da = fmaf(qreg[i + 3], a4.w, da);
        db = fmaf(qreg[i], c4.x, db); db = fmaf(qreg[i + 1], c4.y, db);
        db = fmaf(qreg[i + 2], c4.z, db); db = fmaf(qreg[i + 3], c4.w, db);
      }
    }
    float part = wa * da + wb_ * db;
    part += __shfl_xor(part, 1, 64);
    float logit = part * 0.25f;

    float m = logit;
#pragma unroll
    for (int s = 32; s > 0; s >>= 1) m = fmaxf(m, __shfl_xor(m, s, 64));
    float e = __expf(logit - m);
    float ssum = e;
#pragma unroll
    for (int s = 32; s > 0; s >>= 1) ssum += __shfl_xor(ssum, s, 64);
    float a = e * 2.f / ssum;   // ssum double-counts each point

    // per-wave tables; same-wave LDS RAW/WAR is lgkmcnt-ordered, no barrier
    s_w[wave][pt][2 * h + 0] = a * wa;
    s_w[wave][pt][2 * h + 1] = a * wb_;
    s_i[wave][pt][2 * h + 0] = pa;
    s_i[wave][pt][2 * h + 1] = pb;

    const short* vb = v_t + (size_t)b * NL * 128;
    float o0 = 0.f, o1 = 0.f;
    for (int pp = 0; pp < 32; pp++) {
#pragma unroll
      for (int t = 0; t < 4; t++) {
        float w  = s_w[wave][pp][t];
        int  pix = s_i[wave][pp][t];
        unsigned int u = *(const unsigned int*)(vb + (size_t)pix * 128 + c);
        o0 = fmaf(w, bfbits2f(u & 0xffffu), o0);
        o1 = fmaf(w, bfbits2f(u >> 16), o1);
      }
    }
    unsigned int pk = (unsigned int)f2bf(o0) | ((unsigned int)f2bf(o1) << 16);
    *(unsigned int*)(attn_s + (wave * 4 + jj) * 136 + c) = pk;
  }
  __syncthreads();

  // ---- phase F: final GEMM, N=16 (this block), M=256 over 4 waves ----
  const int quad = lane >> 4, id = lane & 15;
  const int m0 = wave * 64;
  const int pix = pix0 + id;

  // hoist the 12 B-frags (K=384) into registers
  s8v bfr[12];
#pragma unroll
  for (int k4 = 0; k4 < 4; k4++)
    bfr[k4] = *(const s8v*)(attn_s + id * 136 + quad * 8 + k4 * 32);
#pragma unroll
  for (int k8 = 0; k8 < 8; k8++)
    bfr[4 + k8] = *(const s8v*)(xh + (size_t)pix * 256 + quad * 8 + k8 * 32);

  f32x4 acc[4];
#pragma unroll
  for (int mf = 0; mf < 4; mf++) acc[mf] = (f32x4){0.f, 0.f, 0.f, 0.f};
  const short* ap[4];
#pragma unroll
  for (int mf = 0; mf < 4; mf++)
    ap[mf] = wb + (size_t)(m0 + mf * 16 + id) * 384 + quad * 8;

#pragma unroll
  for (int k = 0; k < 12; k++) {
#pragma unroll
    for (int mf = 0; mf < 4; mf++)
      acc[mf] = __builtin_amdgcn_mfma_f32_16x16x32_bf16(
          *(const s8v*)(ap[mf] + k * 32), bfr[k], acc[mf], 0, 0, 0);
  }

  const int bb = pix >> 12, nlow = pix & (NL - 1);
#pragma unroll
  for (int mf = 0; mf < 4; mf++) {
    int mbase = m0 + mf * 16 + quad * 4;
#pragma unroll
    for (int r = 0; r < 4; r++) {
      int o = mbase + r;
      float s  = gamma[o] * rsqrtf(rvar[o] + 1e-5f);
      float sh = beta[o] - rmean[o] * s;
      out[((size_t)bb * 256 + o) * NL + nlow] = fmaxf(fmaf(acc[mf][r], s, sh), 0.f);
    }
  }
}

// ---------------------------------------------------------------------------
extern "C" void kernel_launch(void* const* d_in, const int* in_sizes, int n_in,
                              void* d_out, int out_size, void* d_ws, size_t ws_size,
                              hipStream_t stream) {
  const float* low   = (const float*)d_in[0];
  const float* high  = (const float*)d_in[1];
  const float* W1    = (const float*)d_in[2];
  const float* b1    = (const float*)d_in[3];
  const float* W2    = (const float*)d_in[4];
  const float* b2    = (const float*)d_in[5];
  const float* Wq    = (const float*)d_in[6];
  const float* bq    = (const float*)d_in[7];
  const float* Wk    = (const float*)d_in[8];
  const float* bk    = (const float*)d_in[9];
  const float* Wv    = (const float*)d_in[10];
  const float* bv    = (const float*)d_in[11];
  const float* Woff  = (const float*)d_in[12];
  const float* boff  = (const float*)d_in[13];
  const float* Wb    = (const float*)d_in[14];
  const float* gamma = (const float*)d_in[15];
  const float* beta  = (const float*)d_in[16];
  const float* rmean = (const float*)d_in[17];
  const float* rvar  = (const float*)d_in[18];
  float* out = (float*)d_out;

  short* ws    = (short*)d_ws;
  short* xh    = ws;                    // [8192][256] bf16 = 2,097,152 sh
  short* v_t   = xh + 2097152;          // [8192][128] bf16
  short* wc    = v_t + 1048576;         // 225,280 bf16
  float* q_t   = (float*)(wc + 225280); // [8192][16] f32
  float* k_t   = q_t + 131072;          // [8192][16] f32
  float* off_t = k_t + 131072;          // [8192][64] f32

  convert_weights_k<<<880, 256, 0, stream>>>(W1, W2, Wq, Woff, Wk, Wv, Wb, wc);
  k1_fused<<<512, 256, 0, stream>>>(low, high, wc, b1, b2, bq, boff, bk, bv,
                                    xh, q_t, k_t, off_t, v_t);
  k2_fused<<<512, 256, 0, stream>>>(q_t, k_t, v_t, off_t, xh, wc + 126976,
                                    gamma, beta, rmean, rvar, out);
}

// Round 8
// 154.503 us; speedup vs baseline: 3.4349x; 1.0382x over previous
//
#include <hip/hip_runtime.h>
#include <hip/hip_bf16.h>

#define NL 4096   // 64*64 low-res pixels
#define HH 32
#define WH 32

typedef __attribute__((ext_vector_type(8))) short s8v;   // 8 bf16 MFMA A/B frag
typedef __attribute__((ext_vector_type(4))) short s4v;   // 4 bf16 (8B)
typedef __attribute__((ext_vector_type(4))) float f32x4; // MFMA C/D frag

static __device__ inline unsigned short f2bf(float x) {
  __hip_bfloat16 h = __float2bfloat16(x);   // RNE
  return *reinterpret_cast<unsigned short*>(&h);
}
static __device__ inline float bfbits2f(unsigned int lo16) {
  unsigned int u = lo16 << 16;
  return *reinterpret_cast<float*>(&u);
}

// ---------------------------------------------------------------------------
// Weight fp32 -> bf16, packed:
//   [0,65536)        W1   [128][512]
//   [65536,98304)    W2   [128][256]
//   [98304,100352)   Wq   [16][128]   \
//   [100352,108544)  Woff [64][128]    | stage-B concat: 224 rows, K=128
//   [108544,110592)  Wk   [16][128]    |
//   [110592,126976)  Wv   [128][128]  /
//   [126976,225280)  Wb   [256][384]
// ---------------------------------------------------------------------------
__global__ __launch_bounds__(256) void convert_weights_k(
    const float* __restrict__ w1, const float* __restrict__ w2,
    const float* __restrict__ wq, const float* __restrict__ woff,
    const float* __restrict__ wk, const float* __restrict__ wv,
    const float* __restrict__ wb, short* __restrict__ dst) {
  int i = blockIdx.x * 256 + threadIdx.x;
  const float* src; int off;
  if      (i <  65536) { src = w1;   off = 0; }
  else if (i <  98304) { src = w2;   off = 65536; }
  else if (i < 100352) { src = wq;   off = 98304; }
  else if (i < 108544) { src = woff; off = 100352; }
  else if (i < 110592) { src = wk;   off = 108544; }
  else if (i < 126976) { src = wv;   off = 110592; }
  else if (i < 225280) { src = wb;   off = 126976; }
  else return;
  dst[i] = (short)f2bf(src[i - off]);
}

// ---------------------------------------------------------------------------
// K1: fused prep + stageA + stageB (unchanged from round 6/7).
// 512 blocks x 256 thr; block handles 16 pixels end-to-end.
// ---------------------------------------------------------------------------
__global__ __launch_bounds__(256) void k1_fused(
    const float* __restrict__ low, const float* __restrict__ high,
    const short* __restrict__ wc,
    const float* __restrict__ b1, const float* __restrict__ b2,
    const float* __restrict__ bq, const float* __restrict__ boff,
    const float* __restrict__ bk, const float* __restrict__ bv,
    short* __restrict__ xh, float* __restrict__ q_t, float* __restrict__ k_t,
    float* __restrict__ off_t, short* __restrict__ v_t) {
  __shared__ short xin_s[16 * 520];
  __shared__ short qf_s[16 * 136];
  __shared__ short vf_s[16 * 136];
  const int tid = threadIdx.x;
  const int pix0 = blockIdx.x * 16;
  const int b = pix0 >> 12;
  const int n0 = pix0 & (NL - 1);

  // ---- phase P: build xin tile ----
  {
    const int nl = tid & 15, cg = tid >> 4;
    const int n = n0 + nl;
    const int y = n >> 6, x = n & 63;
    float sx = x * 0.5f - 0.25f;
    float sy = y * 0.5f - 0.25f;
    float x0f = floorf(sx), y0f = floorf(sy);
    float wx = sx - x0f, wy = sy - y0f;
    int x0i = (int)x0f, y0i = (int)y0f;
    int x0c = min(WH - 1, max(0, x0i)), x1c = min(WH - 1, max(0, x0i + 1));
    int y0c = min(HH - 1, max(0, y0i)), y1c = min(HH - 1, max(0, y0i + 1));
    float w00 = (1.f - wy) * (1.f - wx), w01 = (1.f - wy) * wx;
    float w10 = wy * (1.f - wx),         w11 = wy * wx;
#pragma unroll
    for (int i = 0; i < 16; i++) {
      int c = cg * 16 + i;
      const float* f = high + (size_t)(b * 256 + c) * (HH * WH);
      float v = w00 * f[y0c * WH + x0c] + w01 * f[y0c * WH + x1c]
              + w10 * f[y1c * WH + x0c] + w11 * f[y1c * WH + x1c];
      xin_s[nl * 520 + c] = (short)f2bf(v);
      xin_s[nl * 520 + 256 + c] =
          (short)f2bf(low[(size_t)(b * 256 + c) * NL + n]);
    }
  }
  __syncthreads();

  // ---- store xh (high half of xin, needed by K2 final GEMM) ----
  {
    const int r = tid >> 4, c0 = (tid & 15) * 16;
    s8v v0 = *(const s8v*)(xin_s + r * 520 + c0);
    s8v v1 = *(const s8v*)(xin_s + r * 520 + c0 + 8);
    *(s8v*)(xh + (size_t)(pix0 + r) * 256 + c0) = v0;
    *(s8v*)(xh + (size_t)(pix0 + r) * 256 + c0 + 8) = v1;
  }

  const int wave = tid >> 6, lane = tid & 63;
  const int quad = lane >> 4, id = lane & 15;

  // ---- phase A1: qf = W1 @ xin, M=128 K=512 ----
  {
    f32x4 acc0 = (f32x4){0.f, 0.f, 0.f, 0.f};
    f32x4 acc1 = (f32x4){0.f, 0.f, 0.f, 0.f};
    const short* a0 = wc + (size_t)(wave * 32 + id) * 512 + quad * 8;
    const short* a1 = a0 + 16 * 512;
    const short* bp = xin_s + id * 520 + quad * 8;
#pragma unroll
    for (int kk = 0; kk < 512; kk += 32) {
      s8v bf = *(const s8v*)(bp + kk);
      acc0 = __builtin_amdgcn_mfma_f32_16x16x32_bf16(*(const s8v*)(a0 + kk), bf, acc0, 0, 0, 0);
      acc1 = __builtin_amdgcn_mfma_f32_16x16x32_bf16(*(const s8v*)(a1 + kk), bf, acc1, 0, 0, 0);
    }
    int m0 = wave * 32 + quad * 4;
    s4v o0, o1;
#pragma unroll
    for (int r = 0; r < 4; r++) {
      o0[r] = (short)f2bf(acc0[r] + b1[m0 + r]);
      o1[r] = (short)f2bf(acc1[r] + b1[m0 + 16 + r]);
    }
    *(s4v*)(qf_s + id * 136 + m0) = o0;
    *(s4v*)(qf_s + id * 136 + m0 + 16) = o1;
  }

  // ---- phase A2: vf = W2 @ xin[:,0:256], M=128 K=256 ----
  {
    f32x4 acc0 = (f32x4){0.f, 0.f, 0.f, 0.f};
    f32x4 acc1 = (f32x4){0.f, 0.f, 0.f, 0.f};
    const short* a0 = wc + 65536 + (size_t)(wave * 32 + id) * 256 + quad * 8;
    const short* a1 = a0 + 16 * 256;
    const short* bp = xin_s + id * 520 + quad * 8;
#pragma unroll
    for (int kk = 0; kk < 256; kk += 32) {
      s8v bf = *(const s8v*)(bp + kk);
      acc0 = __builtin_amdgcn_mfma_f32_16x16x32_bf16(*(const s8v*)(a0 + kk), bf, acc0, 0, 0, 0);
      acc1 = __builtin_amdgcn_mfma_f32_16x16x32_bf16(*(const s8v*)(a1 + kk), bf, acc1, 0, 0, 0);
    }
    int m0 = wave * 32 + quad * 4;
    s4v o0, o1;
#pragma unroll
    for (int r = 0; r < 4; r++) {
      o0[r] = (short)f2bf(acc0[r] + b2[m0 + r]);
      o1[r] = (short)f2bf(acc1[r] + b2[m0 + 16 + r]);
    }
    *(s4v*)(vf_s + id * 136 + m0) = o0;
    *(s4v*)(vf_s + id * 136 + m0 + 16) = o1;
  }
  __syncthreads();

  // ---- phase B: 14 m-frags (0:q, 1-4:off, 5:k, 6-13:v), K=128 ----
  for (int f = wave; f < 14; f += 4) {
    const short* ap = wc + 98304 + (size_t)(f * 16 + id) * 128 + quad * 8;
    const short* bp = (f < 5 ? qf_s : vf_s) + id * 136 + quad * 8;
    f32x4 acc = (f32x4){0.f, 0.f, 0.f, 0.f};
#pragma unroll
    for (int kk = 0; kk < 128; kk += 32)
      acc = __builtin_amdgcn_mfma_f32_16x16x32_bf16(
          *(const s8v*)(ap + kk), *(const s8v*)(bp + kk), acc, 0, 0, 0);
    const int pix = pix0 + id;
    const int mq = quad * 4;
    if (f == 0) {
      f32x4 v;
#pragma unroll
      for (int r = 0; r < 4; r++) v[r] = acc[r] + bq[mq + r];
      *(f32x4*)(q_t + (size_t)pix * 16 + mq) = v;
    } else if (f < 5) {
      int m = (f - 1) * 16 + mq;
      f32x4 v;
#pragma unroll
      for (int r = 0; r < 4; r++) v[r] = acc[r] + boff[m + r];
      *(f32x4*)(off_t + (size_t)pix * 64 + m) = v;
    } else if (f == 5) {
      f32x4 v;
#pragma unroll
      for (int r = 0; r < 4; r++) v[r] = acc[r] + bk[mq + r];
      *(f32x4*)(k_t + (size_t)pix * 16 + mq) = v;
    } else {
      int m = (f - 6) * 16 + mq;
      s4v o;
#pragma unroll
      for (int r = 0; r < 4; r++) o[r] = (short)f2bf(acc[r] + bv[m + r]);
      *(s4v*)(v_t + (size_t)pix * 128 + m) = o;
    }
  }
}

// ---------------------------------------------------------------------------
// K2: fused deformable attention + final GEMM (+BN+ReLU).
// 512 blocks x 1024 thr (16 waves). Wave w owns query pix0+w (1 query/wave,
// 32 waves/CU). V-gather is tap-parallel: lane = (t=lane>>4, chunk=lane&15),
// one dwordx4 (8 bf16 ch) per point per lane; 32 loads/query (was 128).
// Then F: out[:,n] = ReLU(BN(Wb @ [attn;xh])), M=256 over 16 waves.
// ---------------------------------------------------------------------------
__global__ __launch_bounds__(1024, 2) void k2_fused(
    const float* __restrict__ q_t, const float* __restrict__ k_t,
    const short* __restrict__ v_t, const float* __restrict__ off_t,
    const short* __restrict__ xh, const short* __restrict__ wb,
    const float* __restrict__ gamma, const float* __restrict__ beta,
    const float* __restrict__ rmean, const float* __restrict__ rvar,
    float* __restrict__ out) {
  __shared__ float s_w[16][32][4];   // 8 KB
  __shared__ int   s_i[16][32][4];   // 8 KB
  __shared__ short attn_s[16 * 136]; // 4.25 KB
  const int tid = threadIdx.x;
  const int wave = tid >> 6, lane = tid & 63;
  const int pix0 = blockIdx.x * 16;

  // ---- phase T: attention, ONE query per wave ----
  {
    const int qidx = pix0 + wave;
    const int b = qidx >> 12;
    const int n = qidx & (NL - 1);
    const int qy = n >> 6, qx = n & 63;

    const float* qp = q_t + (size_t)qidx * 16;
    float qreg[16];
#pragma unroll
    for (int i = 0; i < 16; i += 4) {
      float4 t = *(const float4*)(qp + i);
      qreg[i] = t.x; qreg[i + 1] = t.y; qreg[i + 2] = t.z; qreg[i + 3] = t.w;
    }

    const int pt = lane >> 1, h = lane & 1;
    float2 dxy = *(const float2*)(off_t + (size_t)qidx * 64 + 2 * pt);
    float sx = (float)qx + dxy.x;
    float sy = (float)qy + dxy.y;
    float x0f = floorf(sx), y0f = floorf(sy);
    float wx = sx - x0f, wy = sy - y0f;
    int x0i = (int)x0f, y0i = (int)y0f;
    int x0 = min(63, max(0, x0i)), x1 = min(63, max(0, x0i + 1));
    int y0 = min(63, max(0, y0i)), y1 = min(63, max(0, y0i + 1));

    int   yr  = h ? y1 : y0;
    float wyr = h ? wy : (1.f - wy);
    int   pa = yr * 64 + x0, pb = yr * 64 + x1;
    float wa = wyr * (1.f - wx), wb_ = wyr * wx;

    const float* kb = k_t + (size_t)b * NL * 16;
    float da = 0.f, db = 0.f;
    {
      const float* ka = kb + (size_t)pa * 16;
      const float* kc = kb + (size_t)pb * 16;
#pragma unroll
      for (int i = 0; i < 16; i += 4) {
        float4 a4 = *(const float4*)(ka + i);
        float4 c4 = *(const float4*)(kc + i);
        da = fmaf(qreg[i], a4.x, da); da = fmaf(qreg[i + 1], a4.y, da);
        da = fmaf(qreg[i + 2], a4.z, da); da = fmaf(qreg[i + 3], a4.w, da);
        db = fmaf(qreg[i], c4.x, db); db = fmaf(qreg[i + 1], c4.y, db);
        db = fmaf(qreg[i + 2], c4.z, db); db = fmaf(qreg[i + 3], c4.w, db);
      }
    }
    float part = wa * da + wb_ * db;
    part += __shfl_xor(part, 1, 64);
    float logit = part * 0.25f;

    float m = logit;
#pragma unroll
    for (int s = 32; s > 0; s >>= 1) m = fmaxf(m, __shfl_xor(m, s, 64));
    float e = __expf(logit - m);
    float ssum = e;
#pragma unroll
    for (int s = 32; s > 0; s >>= 1) ssum += __shfl_xor(ssum, s, 64);
    float a = e * 2.f / ssum;   // ssum double-counts each point

    // per-wave tables; same-wave LDS RAW is lgkmcnt-ordered -> no barrier
    s_w[wave][pt][2 * h + 0] = a * wa;
    s_w[wave][pt][2 * h + 1] = a * wb_;
    s_i[wave][pt][2 * h + 0] = pa;
    s_i[wave][pt][2 * h + 1] = pb;

    // ---- V-gather: tap-parallel, 8 channels per lane per point ----
    const int t = lane >> 4, chunk = lane & 15;
    const short* vb = v_t + (size_t)b * NL * 128 + chunk * 8;
    float o[8];
#pragma unroll
    for (int j = 0; j < 8; j++) o[j] = 0.f;
#pragma unroll
    for (int pp = 0; pp < 32; pp++) {
      float w_ = s_w[wave][pp][t];
      int  pix = s_i[wave][pp][t];
      uint4 u = *(const uint4*)(vb + (size_t)pix * 128);
      o[0] = fmaf(w_, bfbits2f(u.x & 0xffffu), o[0]);
      o[1] = fmaf(w_, bfbits2f(u.x >> 16),     o[1]);
      o[2] = fmaf(w_, bfbits2f(u.y & 0xffffu), o[2]);
      o[3] = fmaf(w_, bfbits2f(u.y >> 16),     o[3]);
      o[4] = fmaf(w_, bfbits2f(u.z & 0xffffu), o[4]);
      o[5] = fmaf(w_, bfbits2f(u.z >> 16),     o[5]);
      o[6] = fmaf(w_, bfbits2f(u.w & 0xffffu), o[6]);
      o[7] = fmaf(w_, bfbits2f(u.w >> 16),     o[7]);
    }
    // reduce across the 4 tap-groups (lane bits 4,5)
#pragma unroll
    for (int j = 0; j < 8; j++) {
      o[j] += __shfl_xor(o[j], 16, 64);
      o[j] += __shfl_xor(o[j], 32, 64);
    }
    if (t == 0) {
      uint4 pk;
      pk.x = (unsigned)f2bf(o[0]) | ((unsigned)f2bf(o[1]) << 16);
      pk.y = (unsigned)f2bf(o[2]) | ((unsigned)f2bf(o[3]) << 16);
      pk.z = (unsigned)f2bf(o[4]) | ((unsigned)f2bf(o[5]) << 16);
      pk.w = (unsigned)f2bf(o[6]) | ((unsigned)f2bf(o[7]) << 16);
      *(uint4*)(attn_s + wave * 136 + chunk * 8) = pk;
    }
  }
  __syncthreads();

  // ---- phase F: final GEMM, N=16 px, M=256 over 16 waves (1 frag/wave) ----
  {
    const int quad = lane >> 4, id = lane & 15;
    const int m0 = wave * 16;
    const int pix = pix0 + id;

    f32x4 acc = (f32x4){0.f, 0.f, 0.f, 0.f};
    const short* ap = wb + (size_t)(m0 + id) * 384 + quad * 8;
    const short* bs = attn_s + id * 136 + quad * 8;
    const short* bg = xh + (size_t)pix * 256 + quad * 8;
#pragma unroll
    for (int k = 0; k < 4; k++)
      acc = __builtin_amdgcn_mfma_f32_16x16x32_bf16(
          *(const s8v*)(ap + k * 32), *(const s8v*)(bs + k * 32), acc, 0, 0, 0);
#pragma unroll
    for (int k = 0; k < 8; k++)
      acc = __builtin_amdgcn_mfma_f32_16x16x32_bf16(
          *(const s8v*)(ap + 128 + k * 32), *(const s8v*)(bg + k * 32), acc, 0, 0, 0);

    const int bb = pix >> 12, nlow = pix & (NL - 1);
    const int mbase = m0 + quad * 4;
#pragma unroll
    for (int r = 0; r < 4; r++) {
      int o = mbase + r;
      float s  = gamma[o] * rsqrtf(rvar[o] + 1e-5f);
      float sh = beta[o] - rmean[o] * s;
      out[((size_t)bb * 256 + o) * NL + nlow] = fmaxf(fmaf(acc[r], s, sh), 0.f);
    }
  }
}

// ---------------------------------------------------------------------------
extern "C" void kernel_launch(void* const* d_in, const int* in_sizes, int n_in,
                              void* d_out, int out_size, void* d_ws, size_t ws_size,
                              hipStream_t stream) {
  const float* low   = (const float*)d_in[0];
  const float* high  = (const float*)d_in[1];
  const float* W1    = (const float*)d_in[2];
  const float* b1    = (const float*)d_in[3];
  const float* W2    = (const float*)d_in[4];
  const float* b2    = (const float*)d_in[5];
  const float* Wq    = (const float*)d_in[6];
  const float* bq    = (const float*)d_in[7];
  const float* Wk    = (const float*)d_in[8];
  const float* bk    = (const float*)d_in[9];
  const float* Wv    = (const float*)d_in[10];
  const float* bv    = (const float*)d_in[11];
  const float* Woff  = (const float*)d_in[12];
  const float* boff  = (const float*)d_in[13];
  const float* Wb    = (const float*)d_in[14];
  const float* gamma = (const float*)d_in[15];
  const float* beta  = (const float*)d_in[16];
  const float* rmean = (const float*)d_in[17];
  const float* rvar  = (const float*)d_in[18];
  float* out = (float*)d_out;

  short* ws    = (short*)d_ws;
  short* xh    = ws;                    // [8192][256] bf16 = 2,097,152 sh
  short* v_t   = xh + 2097152;          // [8192][128] bf16
  short* wc    = v_t + 1048576;         // 225,280 bf16
  float* q_t   = (float*)(wc + 225280); // [8192][16] f32
  float* k_t   = q_t + 131072;          // [8192][16] f32
  float* off_t = k_t + 131072;          // [8192][64] f32

  convert_weights_k<<<880, 256, 0, stream>>>(W1, W2, Wq, Woff, Wk, Wv, Wb, wc);
  k1_fused<<<512, 256, 0, stream>>>(low, high, wc, b1, b2, bq, boff, bk, bv,
                                    xh, q_t, k_t, off_t, v_t);
  k2_fused<<<512, 1024, 0, stream>>>(q_t, k_t, v_t, off_t, xh, wc + 126976,
                                     gamma, beta, rmean, rvar, out);
}